// Round 2
// 2277.174 us; speedup vs baseline: 1.2821x; 1.2821x over previous
//
#include <hip/hip_runtime.h>
#include <hip/hip_bf16.h>

#define N_NODES 50000
#define N_EDGES 800000
#define F_IN    768
#define H_DIM   256
#define N_B     32
#define N_G     4
#define C1      1280
#define C2      640

typedef unsigned short u16;
typedef unsigned int u32;
typedef __bf16 bf16x8 __attribute__((ext_vector_type(8)));
typedef float f32x4 __attribute__((ext_vector_type(4)));

__device__ inline u16 f2b(float f) {
    u32 u = __builtin_bit_cast(u32, f);
    u += 0x7fffu + ((u >> 16) & 1u);   // RNE (finite values)
    return (u16)(u >> 16);
}
__device__ inline float b2f(u16 h) {
    u32 u = ((u32)h) << 16;
    return __builtin_bit_cast(float, u);
}
__device__ inline u32 pack2(float a, float b) {
    return (u32)f2b(a) | ((u32)f2b(b) << 16);
}

// ---------------- CSR build ----------------

__global__ void count_deg_kernel(const int* __restrict__ dst, int* __restrict__ deg, int n_edges) {
    int e = blockIdx.x * blockDim.x + threadIdx.x;
    if (e < n_edges) atomicAdd(&deg[dst[e]], 1);
}

// scan pass 1: per-block (1024-wide) totals
__global__ __launch_bounds__(1024) void scan1_kernel(const int* __restrict__ deg,
                                                     int* __restrict__ bsum, int n) {
    __shared__ int ws[16];
    int tid = threadIdx.x, lane = tid & 63, wid = tid >> 6;
    int i = blockIdx.x * 1024 + tid;
    int x = (i < n) ? deg[i] : 0;
#pragma unroll
    for (int off = 32; off; off >>= 1) x += __shfl_xor(x, off, 64);
    if (lane == 0) ws[wid] = x;
    __syncthreads();
    if (tid == 0) {
        int s = 0;
#pragma unroll
        for (int w = 0; w < 16; w++) s += ws[w];
        bsum[blockIdx.x] = s;
    }
}

// scan pass 2: exclusive scan of block totals (nb <= 64), also writes row_start[n]=total
__global__ __launch_bounds__(64) void scan2_kernel(int* __restrict__ bsum, int nb,
                                                   int* __restrict__ row_start, int n) {
    int lane = threadIdx.x;
    int x = (lane < nb) ? bsum[lane] : 0;
    int v = x;
#pragma unroll
    for (int off = 1; off < 64; off <<= 1) {
        int t = __shfl_up(v, off, 64);
        if (lane >= off) v += t;
    }
    if (lane < nb) bsum[lane] = v - x;  // exclusive
    if (lane == 63) row_start[n] = v;   // grand total
}

// scan pass 3: local exclusive scan + block offset; also dinv
__global__ __launch_bounds__(1024) void scan3_kernel(const int* __restrict__ deg,
                                                     const int* __restrict__ bsum,
                                                     int* __restrict__ row_start,
                                                     int* __restrict__ cursor,
                                                     float* __restrict__ dinv, int n) {
    __shared__ int ws[16];
    int tid = threadIdx.x, lane = tid & 63, wid = tid >> 6;
    int i = blockIdx.x * 1024 + tid;
    int x = (i < n) ? deg[i] : 0;
    int v = x;
#pragma unroll
    for (int off = 1; off < 64; off <<= 1) {
        int t = __shfl_up(v, off, 64);
        if (lane >= off) v += t;
    }
    if (lane == 63) ws[wid] = v;
    __syncthreads();
    if (wid == 0) {
        int s = (lane < 16) ? ws[lane] : 0;
#pragma unroll
        for (int off = 1; off < 16; off <<= 1) {
            int t = __shfl_up(s, off, 64);
            if (lane >= off) s += t;
        }
        if (lane < 16) ws[lane] = s;
    }
    __syncthreads();
    if (i < n) {
        int excl = bsum[blockIdx.x] + (wid ? ws[wid - 1] : 0) + (v - x);
        row_start[i] = excl;
        cursor[i] = excl;
        dinv[i] = rsqrtf((float)(x + 1));  // self-loop included
    }
}

__global__ void fill_csr_kernel(const int* __restrict__ src, const int* __restrict__ dst,
                                int* __restrict__ cursor, int* __restrict__ csr_src, int n_edges) {
    int e = blockIdx.x * blockDim.x + threadIdx.x;
    if (e < n_edges) {
        int d = dst[e];
        int pos = atomicAdd(&cursor[d], 1);
        csr_src[pos] = src[e];
    }
}

// ---------------- weight prep: W[K][256] fp32 -> Wt[256][K] bf16 ----------------

__global__ void prep_w_kernel(const float* __restrict__ W, u16* __restrict__ Wt, int K) {
    int idx = blockIdx.x * blockDim.x + threadIdx.x;
    if (idx >= K * 256) return;
    int k = idx >> 8, n = idx & 255;
    Wt[(size_t)n * K + k] = f2b(W[idx]);
}

// ---------------- MFMA GEMM: C[i][c] = bf16( dinv[i] * sum_k A[i][k]*W[k][c] ) --------
// A: [n,K] (fp32 or bf16, row-major), Wt: [256][K] bf16 (transposed), C: [n,256] bf16.
// 64x256 tile (full N-dim in one block -> A read exactly once), BK=32, 256 threads,
// wave w owns a 64-col stripe; 4x4 MFMA 16x16x32 tiles per wave.

__global__ __launch_bounds__(256) void gemm_mfma_kernel(const void* __restrict__ Aptr, int a_fp32,
                                                        const u16* __restrict__ Wt,
                                                        const float* __restrict__ dinv,
                                                        u16* __restrict__ Cout, int n, int K) {
    __shared__ u16 As[64 * 32] __attribute__((aligned(16)));    // 4 KiB
    __shared__ u16 Bs[256 * 32] __attribute__((aligned(16)));   // 16 KiB
    int tid = threadIdx.x;
    int row0 = blockIdx.x * 64;
    int wid = tid >> 6, lane = tid & 63;
    int mlane = lane & 15, kg = lane >> 4;

    int ra = tid >> 2;                 // 0..63
    int koffa = (tid & 3) << 3;        // 0,8,16,24
    int rga = row0 + ra; if (rga >= n) rga = n - 1;

    f32x4 acc[4][4];
#pragma unroll
    for (int a = 0; a < 4; a++)
#pragma unroll
        for (int b = 0; b < 4; b++)
#pragma unroll
            for (int c = 0; c < 4; c++) acc[a][b][c] = 0.f;

    for (int k0 = 0; k0 < K; k0 += 32) {
        // stage A tile [64 rows][32 k] bf16
        if (a_fp32) {
            const float* A = (const float*)Aptr;
            const float* srcp = A + (size_t)rga * K + k0 + koffa;
            float4 f0 = *(const float4*)srcp;
            float4 f1 = *(const float4*)(srcp + 4);
            int4 v;
            v.x = (int)pack2(f0.x, f0.y);
            v.y = (int)pack2(f0.z, f0.w);
            v.z = (int)pack2(f1.x, f1.y);
            v.w = (int)pack2(f1.z, f1.w);
            *(int4*)&As[ra * 32 + koffa] = v;
        } else {
            const u16* A = (const u16*)Aptr;
            *(int4*)&As[ra * 32 + koffa] = *(const int4*)(A + (size_t)rga * K + k0 + koffa);
        }
        // stage B tile: Bs[256][32] from Wt
#pragma unroll
        for (int it = 0; it < 4; it++) {
            int c = tid + it * 256;
            int r = c >> 2;
            int koff = (c & 3) << 3;
            *(int4*)&Bs[r * 32 + koff] = *(const int4*)(Wt + (size_t)r * K + k0 + koff);
        }
        __syncthreads();
        bf16x8 af[4], bfv[4];
#pragma unroll
        for (int mi = 0; mi < 4; mi++)
            af[mi] = *(const bf16x8*)&As[(mi * 16 + mlane) * 32 + kg * 8];
#pragma unroll
        for (int ni = 0; ni < 4; ni++)
            bfv[ni] = *(const bf16x8*)&Bs[(wid * 64 + ni * 16 + mlane) * 32 + kg * 8];
#pragma unroll
        for (int mi = 0; mi < 4; mi++)
#pragma unroll
            for (int ni = 0; ni < 4; ni++)
                acc[mi][ni] = __builtin_amdgcn_mfma_f32_16x16x32_bf16(af[mi], bfv[ni], acc[mi][ni], 0, 0, 0);
        __syncthreads();
    }
    // epilogue: C/D layout col=lane&15, row=(lane>>4)*4+reg
#pragma unroll
    for (int mi = 0; mi < 4; mi++) {
        int rbase = row0 + mi * 16 + kg * 4;
#pragma unroll
        for (int r = 0; r < 4; r++) {
            int row = rbase + r;
            if (row < n) {
                float s = dinv[row];
#pragma unroll
                for (int ni = 0; ni < 4; ni++) {
                    int col = wid * 64 + ni * 16 + mlane;
                    Cout[(size_t)row * H_DIM + col] = f2b(acc[mi][ni][r] * s);
                }
            }
        }
    }
}

// ---------------- Aggregation: out[i] = maybe_relu(dinv[i]*(Ht[i] + sum_j Ht[j]) + b) --------

__global__ __launch_bounds__(64) void aggregate_kernel(const u16* __restrict__ Ht,
                                                       const int* __restrict__ row_start,
                                                       const int* __restrict__ csr_src,
                                                       const float* __restrict__ dinv,
                                                       const float* __restrict__ bias,
                                                       u16* __restrict__ out, int do_relu) {
    int i = blockIdx.x;
    int c4 = threadIdx.x << 2;
    ushort4 sv = *(const ushort4*)(Ht + (size_t)i * H_DIM + c4);
    float a0 = b2f(sv.x), a1 = b2f(sv.y), a2 = b2f(sv.z), a3 = b2f(sv.w);
    int s = row_start[i], e = row_start[i + 1];
    for (int p = s; p < e; p++) {
        int j = csr_src[p];
        ushort4 v = *(const ushort4*)(Ht + (size_t)j * H_DIM + c4);
        a0 += b2f(v.x); a1 += b2f(v.y); a2 += b2f(v.z); a3 += b2f(v.w);
    }
    float di = dinv[i];
    float4 b = *(const float4*)(bias + c4);
    float o0 = a0 * di + b.x, o1 = a1 * di + b.y, o2 = a2 * di + b.z, o3 = a3 * di + b.w;
    if (do_relu) {
        o0 = fmaxf(o0, 0.f); o1 = fmaxf(o1, 0.f);
        o2 = fmaxf(o2, 0.f); o3 = fmaxf(o3, 0.f);
    }
    ushort4 ov = make_ushort4(f2b(o0), f2b(o1), f2b(o2), f2b(o3));
    *(ushort4*)(out + (size_t)i * H_DIM + c4) = ov;
}

// ---------------- Pooling ----------------
// batch is sorted: each block takes a contiguous node chunk, accumulates per-channel in a
// register, flushes to global with one atomicAdd per (segment boundary, channel).

__global__ __launch_bounds__(256) void pool_kernel(const u16* __restrict__ h3,
                                                   const int* __restrict__ batch,
                                                   float* __restrict__ concat, int g) {
    int tid = threadIdx.x;  // channel 0..255
    int per = (N_NODES + (int)gridDim.x - 1) / (int)gridDim.x;
    int start = blockIdx.x * per;
    int end = min(N_NODES, start + per);
    if (start >= end) return;
    float acc = 0.f;
    int cur = batch[start];
    for (int i = start; i < end; i++) {
        int b = batch[i];
        if (b != cur) {
            atomicAdd(&concat[cur * C1 + g * H_DIM + tid], acc);
            acc = 0.f;
            cur = b;
        }
        acc += b2f(h3[(size_t)i * H_DIM + tid]);
    }
    atomicAdd(&concat[cur * C1 + g * H_DIM + tid], acc);
}

// per-batch node counts via binary search on sorted batch array
__global__ __launch_bounds__(64) void count_kernel(const int* __restrict__ batch,
                                                   float* __restrict__ cnt, int g) {
    __shared__ int bound[N_B + 1];
    int t = threadIdx.x;
    if (t <= N_B) {
        int lo = 0, hi = N_NODES;
        while (lo < hi) {
            int mid = (lo + hi) >> 1;
            if (batch[mid] < t) lo = mid + 1; else hi = mid;
        }
        bound[t] = lo;
    }
    __syncthreads();
    if (t < N_B) cnt[g * N_B + t] = (float)(bound[t + 1] - bound[t]);
}

__global__ void pool_div_kernel(float* __restrict__ concat, const float* __restrict__ cnt) {
    int idx = blockIdx.x * blockDim.x + threadIdx.x;  // 4*32*256
    int g = idx >> 13;
    int r = idx & 8191;
    int b = r >> 8;
    int f = r & 255;
    float c = fmaxf(cnt[g * N_B + b], 1.f);
    concat[b * C1 + g * H_DIM + f] /= c;
}

// ---------------- MLP head (fp32, tiny) ----------------

__global__ void xc_kernel(const float* __restrict__ x_code, const float* __restrict__ Wc,
                          const float* __restrict__ bc, float* __restrict__ concat) {
    int idx = blockIdx.x * blockDim.x + threadIdx.x;  // 32*256
    int b = idx >> 8, c = idx & 255;
    float acc = bc[c];
    for (int k = 0; k < F_IN; k++) acc += x_code[b * F_IN + k] * Wc[k * H_DIM + c];
    concat[b * C1 + 4 * H_DIM + c] = fmaxf(acc, 0.f);
}

__global__ void mlp1_kernel(const float* __restrict__ concat, const float* __restrict__ Wl1,
                            const float* __restrict__ bl1, float* __restrict__ hmid) {
    int idx = blockIdx.x * blockDim.x + threadIdx.x;  // 32*640
    int b = idx / C2, c = idx % C2;
    float acc = bl1[c];
    for (int k = 0; k < C1; k++) acc += concat[b * C1 + k] * Wl1[k * C2 + c];
    hmid[b * C2 + c] = fmaxf(acc, 0.f);
}

__global__ void mlp2_kernel(const float* __restrict__ hmid, const float* __restrict__ Wl2,
                            const float* __restrict__ bl2, float* __restrict__ out) {
    int idx = threadIdx.x;  // 64 = 32*2
    if (idx < N_B * 2) {
        int b = idx >> 1, c = idx & 1;
        float acc = bl2[c];
        for (int k = 0; k < C2; k++) acc += hmid[b * C2 + k] * Wl2[k * 2 + c];
        out[b * 2 + c] = acc;
    }
}

// ---------------- Launch ----------------

extern "C" void kernel_launch(void* const* d_in, const int* in_sizes, int n_in,
                              void* d_out, int out_size, void* d_ws, size_t ws_size,
                              hipStream_t stream) {
    const float* x_g[N_G];
    const int* ei[N_G];
    const int* batch[N_G];
    for (int g = 0; g < N_G; g++) {
        x_g[g]   = (const float*)d_in[3 * g + 0];
        ei[g]    = (const int*)d_in[3 * g + 1];
        batch[g] = (const int*)d_in[3 * g + 2];
    }
    const float* x_code = (const float*)d_in[12];
    const float* W1 = (const float*)d_in[13];
    const float* b1 = (const float*)d_in[14];
    const float* W2 = (const float*)d_in[15];
    const float* b2 = (const float*)d_in[16];
    const float* W3 = (const float*)d_in[17];
    const float* b3 = (const float*)d_in[18];
    const float* Wc = (const float*)d_in[19];
    const float* bc = (const float*)d_in[20];
    const float* Wl1 = (const float*)d_in[21];
    const float* bl1 = (const float*)d_in[22];
    const float* Wl2 = (const float*)d_in[23];
    const float* bl2 = (const float*)d_in[24];
    float* out = (float*)d_out;

    char* p = (char*)d_ws;
    auto alloc = [&](size_t bytes) -> void* {
        void* q = (void*)p;
        p += (bytes + 255) & ~(size_t)255;
        return q;
    };
    u16*   bufA      = (u16*)alloc((size_t)N_NODES * H_DIM * 2);
    u16*   bufB      = (u16*)alloc((size_t)N_NODES * H_DIM * 2);
    u16*   Wt1       = (u16*)alloc((size_t)H_DIM * F_IN * 2);
    u16*   Wt2       = (u16*)alloc((size_t)H_DIM * H_DIM * 2);
    u16*   Wt3       = (u16*)alloc((size_t)H_DIM * H_DIM * 2);
    int*   row_start = (int*)alloc((size_t)(N_NODES + 1) * 4);
    int*   cursor    = (int*)alloc((size_t)N_NODES * 4);
    int*   csr_src   = (int*)alloc((size_t)N_EDGES * 4);
    int*   deg       = (int*)alloc((size_t)N_NODES * 4);
    float* dinv      = (float*)alloc((size_t)N_NODES * 4);
    float* concat    = (float*)alloc((size_t)N_B * C1 * 4);
    float* cnt       = (float*)alloc((size_t)N_G * N_B * 4);
    float* hmid      = (float*)alloc((size_t)N_B * C2 * 4);
    int*   bsum      = (int*)alloc((size_t)64 * 4);

    hipMemsetAsync(concat, 0, (size_t)N_B * C1 * 4, stream);

    // weight prep (bf16 transposed)
    prep_w_kernel<<<(F_IN * 256 + 255) / 256, 256, 0, stream>>>(W1, Wt1, F_IN);
    prep_w_kernel<<<(H_DIM * 256 + 255) / 256, 256, 0, stream>>>(W2, Wt2, H_DIM);
    prep_w_kernel<<<(H_DIM * 256 + 255) / 256, 256, 0, stream>>>(W3, Wt3, H_DIM);

    dim3 gemm_grid((N_NODES + 63) / 64);
    int nb_scan = (N_NODES + 1023) / 1024;  // 49

    for (int g = 0; g < N_G; g++) {
        const int* src = ei[g];
        const int* dst = ei[g] + N_EDGES;
        hipMemsetAsync(deg, 0, (size_t)N_NODES * 4, stream);
        count_deg_kernel<<<(N_EDGES + 255) / 256, 256, 0, stream>>>(dst, deg, N_EDGES);
        scan1_kernel<<<nb_scan, 1024, 0, stream>>>(deg, bsum, N_NODES);
        scan2_kernel<<<1, 64, 0, stream>>>(bsum, nb_scan, row_start, N_NODES);
        scan3_kernel<<<nb_scan, 1024, 0, stream>>>(deg, bsum, row_start, cursor, dinv, N_NODES);
        fill_csr_kernel<<<(N_EDGES + 255) / 256, 256, 0, stream>>>(src, dst, cursor, csr_src, N_EDGES);

        // layer 1: A = x (fp32), K=768
        gemm_mfma_kernel<<<gemm_grid, 256, 0, stream>>>(x_g[g], 1, Wt1, dinv, bufA, N_NODES, F_IN);
        aggregate_kernel<<<N_NODES, 64, 0, stream>>>(bufA, row_start, csr_src, dinv, b1, bufB, 1);
        // layer 2: A = bufB (bf16), K=256
        gemm_mfma_kernel<<<gemm_grid, 256, 0, stream>>>(bufB, 0, Wt2, dinv, bufA, N_NODES, H_DIM);
        aggregate_kernel<<<N_NODES, 64, 0, stream>>>(bufA, row_start, csr_src, dinv, b2, bufB, 1);
        // layer 3: K=256, no relu
        gemm_mfma_kernel<<<gemm_grid, 256, 0, stream>>>(bufB, 0, Wt3, dinv, bufA, N_NODES, H_DIM);
        aggregate_kernel<<<N_NODES, 64, 0, stream>>>(bufA, row_start, csr_src, dinv, b3, bufB, 0);

        pool_kernel<<<2048, 256, 0, stream>>>(bufB, batch[g], concat, g);
        count_kernel<<<1, 64, 0, stream>>>(batch[g], cnt, g);
    }

    pool_div_kernel<<<(N_G * N_B * H_DIM) / 256, 256, 0, stream>>>(concat, cnt);
    xc_kernel<<<(N_B * H_DIM) / 256, 256, 0, stream>>>(x_code, Wc, bc, concat);
    mlp1_kernel<<<(N_B * C2) / 256, 256, 0, stream>>>(concat, Wl1, bl1, hmid);
    mlp2_kernel<<<1, 64, 0, stream>>>(hmid, Wl2, bl2, out);
}